// Round 1
// baseline (124.004 us; speedup 1.0000x reference)
//
#include <hip/hip_runtime.h>

#define D 128
#define NS 16
#define BATCH 16384
#define TILE 64

typedef __attribute__((ext_vector_type(8))) short short8;
typedef __attribute__((ext_vector_type(4))) float f32x4;

__device__ __forceinline__ unsigned short f2bf(float f) {
  unsigned u = __builtin_bit_cast(unsigned, f);
  u += 0x7FFFu + ((u >> 16) & 1u);   // round-to-nearest-even
  return (unsigned short)(u >> 16);
}

// ---------------------------------------------------------------------------
// prep: blocks [0,128) transpose+convert A/C -> bf16 ws buffers
//       blocks [128,192) build per-state row lists (wave-aggregated atomics)
// ---------------------------------------------------------------------------
__global__ __launch_bounds__(256) void prep_kernel(
    const float* __restrict__ A_all, const float* __restrict__ C_all,
    const int* __restrict__ sidx,
    int* __restrict__ counts, unsigned short* __restrict__ lists,
    unsigned short* __restrict__ At, unsigned short* __restrict__ Ct) {
  const int b = blockIdx.x, tid = threadIdx.x;
  if (b < 128) {
    // per block: one quarter of one 128x128 matrix, 4x4 micro-transpose/thread
    const int mat = b >> 6, r = b & 63, s = r >> 2, sub = r & 3;
    const float* in = (mat ? C_all : A_all) + s * D * D;
    unsigned short* outp = (mat ? Ct : At) + s * D * D;
    const int d0 = (sub * 8 + (tid >> 5)) * 4;
    const int e0 = (tid & 31) * 4;
    float vv[4][4];
#pragma unroll
    for (int i = 0; i < 4; i++) {
      const float4 t = *(const float4*)(in + (d0 + i) * D + e0);
      vv[i][0] = t.x; vv[i][1] = t.y; vv[i][2] = t.z; vv[i][3] = t.w;
    }
#pragma unroll
    for (int j = 0; j < 4; j++) {
      ushort4 wv;
      wv.x = f2bf(vv[0][j]); wv.y = f2bf(vv[1][j]);
      wv.z = f2bf(vv[2][j]); wv.w = f2bf(vv[3][j]);
      *(ushort4*)(outp + (size_t)(e0 + j) * D + d0) = wv;  // out[e][d] = in[d][e]
    }
  } else {
    const int i = (b - 128) * 256 + tid;
    const int s = sidx[i];
    const int lane = tid & 63;
#pragma unroll 1
    for (int ss = 0; ss < NS; ss++) {
      unsigned long long m = __ballot(s == ss);
      if (s == ss) {
        int leader = __ffsll(m) - 1;
        int base = 0;
        if (lane == leader) base = atomicAdd(&counts[ss], (int)__popcll(m));
        base = __shfl(base, leader, 64);
        int rank = __popcll(m & ((1ull << lane) - 1ull));
        lists[(size_t)ss * BATCH + base + rank] = (unsigned short)i;
      }
    }
  }
}

// ---------------------------------------------------------------------------
// main: one block = 64 rows of one state. out = relu(X@A)@C via bf16 MFMA.
//  Xs stride 136 (pad +8) -> 2-way LDS aliasing only (free).
//  B-operand fragments: Ws[n][k], lane reads 8 contiguous k -> ds_read_b128.
//  MFMA 16x16x32 bf16 layouts (HW-verified):
//    A: A[m=lane&15][k=(lane>>4)*8+j]   B: B[k=(lane>>4)*8+j][n=lane&15]
//    C/D: col=lane&15, row=(lane>>4)*4+reg
// ---------------------------------------------------------------------------
__global__ __launch_bounds__(256, 3) void ssm_kernel(
    const float* __restrict__ x,
    const int* __restrict__ counts,
    const unsigned short* __restrict__ lists,
    const unsigned short* __restrict__ At,
    const unsigned short* __restrict__ Ct,
    float* __restrict__ out) {
  __shared__ unsigned short Xs[TILE][136];  // X tile, then relu(X@A) tile
  __shared__ unsigned short Ws[D][136];     // At, then Ct
  __shared__ int rows[TILE];

  const int s = blockIdx.y;
  const int n = counts[s];
  const int row0 = blockIdx.x * TILE;
  if (row0 >= n) return;
  const int nr = min(TILE, n - row0);
  const int tid = threadIdx.x;

  const size_t lb = (size_t)s * BATCH + row0;
  if (tid < TILE) rows[tid] = (tid < nr) ? (int)lists[lb + tid] : -1;

  // ---- stage X (gathered rows, fp32 -> bf16), 4 threads/row ----
  {
    const int r = tid >> 2, q = tid & 3;
    const int rowid = (r < nr) ? (int)lists[lb + r] : -1;
    unsigned short* xr = &Xs[r][q * 32];
    if (rowid >= 0) {
      const float4* src = (const float4*)(x + (size_t)rowid * D + q * 32);
#pragma unroll
      for (int i = 0; i < 8; i++) {
        float4 v = src[i];
        ushort4 p;
        p.x = f2bf(v.x); p.y = f2bf(v.y); p.z = f2bf(v.z); p.w = f2bf(v.w);
        *(ushort4*)(xr + i * 4) = p;
      }
    } else {
      ushort4 z; z.x = z.y = z.z = z.w = 0;
#pragma unroll
      for (int i = 0; i < 8; i++) *(ushort4*)(xr + i * 4) = z;
    }
  }
  // ---- stage At[s] -> Ws ----
  {
    const uint4* g = (const uint4*)(At + (size_t)s * D * D);
#pragma unroll
    for (int c = tid; c < 2048; c += 256)
      *(uint4*)&Ws[c >> 4][(c & 15) * 8] = g[c];
  }
  __syncthreads();

  const int lane = tid & 63, w = tid >> 6;
  const int l15 = lane & 15, quad = lane >> 4;

  f32x4 acc[8];
#pragma unroll
  for (int nb = 0; nb < 8; nb++) acc[nb] = (f32x4){0.f, 0.f, 0.f, 0.f};

  // ---- phase 1: out1 = X @ A  (wave w owns rows 16w..16w+15, all 128 cols)
#pragma unroll
  for (int kb = 0; kb < 4; kb++) {
    short8 aF = *(const short8*)&Xs[w * 16 + l15][kb * 32 + quad * 8];
#pragma unroll
    for (int nb = 0; nb < 8; nb++) {
      short8 bF = *(const short8*)&Ws[nb * 16 + l15][kb * 32 + quad * 8];
      acc[nb] = __builtin_amdgcn_mfma_f32_16x16x32_bf16(aF, bF, acc[nb], 0, 0, 0);
    }
  }
  __syncthreads();  // everyone done reading Xs and Ws

  // ---- relu + C/D-layout -> A-operand relayout through LDS ----
#pragma unroll
  for (int nb = 0; nb < 8; nb++)
#pragma unroll
    for (int r = 0; r < 4; r++) {
      float v = acc[nb][r];
      Xs[w * 16 + quad * 4 + r][nb * 16 + l15] = f2bf(v > 0.f ? v : 0.f);
    }
  // ---- stage Ct[s] -> Ws ----
  {
    const uint4* g = (const uint4*)(Ct + (size_t)s * D * D);
#pragma unroll
    for (int c = tid; c < 2048; c += 256)
      *(uint4*)&Ws[c >> 4][(c & 15) * 8] = g[c];
  }
  __syncthreads();

  // ---- phase 2: out = out1 @ C ----
#pragma unroll
  for (int nb = 0; nb < 8; nb++) acc[nb] = (f32x4){0.f, 0.f, 0.f, 0.f};
#pragma unroll
  for (int kb = 0; kb < 4; kb++) {
    short8 aF = *(const short8*)&Xs[w * 16 + l15][kb * 32 + quad * 8];
#pragma unroll
    for (int nb = 0; nb < 8; nb++) {
      short8 bF = *(const short8*)&Ws[nb * 16 + l15][kb * 32 + quad * 8];
      acc[nb] = __builtin_amdgcn_mfma_f32_16x16x32_bf16(aF, bF, acc[nb], 0, 0, 0);
    }
  }

  // ---- scatter rows back to global (fp32) ----
#pragma unroll
  for (int r = 0; r < 4; r++) {
    const int rl = w * 16 + quad * 4 + r;
    if (rl < nr) {
      float* orow = out + (size_t)rows[rl] * D + l15;
#pragma unroll
      for (int nb = 0; nb < 8; nb++) orow[nb * 16] = acc[nb][r];
    }
  }
}

extern "C" void kernel_launch(void* const* d_in, const int* in_sizes, int n_in,
                              void* d_out, int out_size, void* d_ws, size_t ws_size,
                              hipStream_t stream) {
  const float* x = (const float*)d_in[0];
  const int* sidx = (const int*)d_in[1];
  const float* A_all = (const float*)d_in[2];
  const float* C_all = (const float*)d_in[3];
  float* out = (float*)d_out;

  // ws layout: counts(64B) | lists(512KB u16) | At(512KB bf16) | Ct(512KB bf16)
  int* counts = (int*)d_ws;
  unsigned short* lists = (unsigned short*)((char*)d_ws + 64);
  unsigned short* At = (unsigned short*)((char*)d_ws + 64 + 512 * 1024);
  unsigned short* Ct = At + NS * D * D;

  hipMemsetAsync(counts, 0, 64, stream);
  prep_kernel<<<192, 256, 0, stream>>>(A_all, C_all, sidx, counts, lists, At, Ct);
  ssm_kernel<<<dim3(BATCH / TILE, NS), 256, 0, stream>>>(x, counts, lists, At, Ct, out);
}

// Round 2
// 80.508 us; speedup vs baseline: 1.5403x; 1.5403x over previous
//
#include <hip/hip_runtime.h>

#define D 128
#define NS 16
#define BATCH 16384
#define TILE 64

typedef __attribute__((ext_vector_type(8))) short short8;
typedef __attribute__((ext_vector_type(4))) float f32x4;

__device__ __forceinline__ unsigned short f2bf(float f) {
  unsigned u = __builtin_bit_cast(unsigned, f);
  u += 0x7FFFu + ((u >> 16) & 1u);   // round-to-nearest-even
  return (unsigned short)(u >> 16);
}

// counts are padded: counts[s * 32] (one 128B cacheline per state) to kill
// cross-XCD line ping-pong (R1: 4096 atomics on ONE line -> 48us prep).
#define CPAD 32

// ---------------------------------------------------------------------------
// prep: blocks [0,128): LDS-staged transpose+convert A/C -> bf16 (At[e][d])
//       blocks [128,192): per-state row lists, block-aggregated atomics
// ---------------------------------------------------------------------------
__global__ __launch_bounds__(256) void prep_kernel(
    const float* __restrict__ A_all, const float* __restrict__ C_all,
    const int* __restrict__ sidx,
    int* __restrict__ counts, unsigned short* __restrict__ lists,
    unsigned short* __restrict__ At, unsigned short* __restrict__ Ct) {
  const int b = blockIdx.x, tid = threadIdx.x;
  if (b < 128) {
    // one block = one 128x32 slab of one matrix: transpose through LDS
    __shared__ float T[32][129];  // T[e - e0][d]; stride 129 -> conflict-free-ish
    const int mat = b >> 6, r = b & 63, s = r >> 2, slab = r & 3;
    const float* in = (mat ? C_all : A_all) + (size_t)s * D * D;
    unsigned short* outp = (mat ? Ct : At) + (size_t)s * D * D;
    const int e0 = slab * 32;
    // coalesced load: thread covers in[d][e0+ecol .. +4], 4 d-rows
    const int ecol = (tid & 7) * 4;
    const int drow = tid >> 3;  // 0..31
#pragma unroll
    for (int i = 0; i < 4; i++) {
      const int d = drow + 32 * i;
      const float4 v = *(const float4*)(in + (size_t)d * D + e0 + ecol);
      T[ecol + 0][d] = v.x;
      T[ecol + 1][d] = v.y;
      T[ecol + 2][d] = v.z;
      T[ecol + 3][d] = v.w;
    }
    __syncthreads();
    // coalesced store: thread writes outp[(e0+e)][d0..d0+16] (32 B)
    const int e = tid >> 3;
    const int d0 = (tid & 7) * 16;
    unsigned short p[16];
#pragma unroll
    for (int k = 0; k < 16; k++) p[k] = f2bf(T[e][d0 + k]);
    unsigned short* dst = outp + (size_t)(e0 + e) * D + d0;
    *(uint4*)(dst) = *(const uint4*)(p);
    *(uint4*)(dst + 8) = *(const uint4*)(p + 8);
  } else {
    // row-list builder: ballot per wave -> LDS aggregate -> 16 atomics/block
    __shared__ int wcnt[4][NS];
    __shared__ int woff[4][NS];
    __shared__ int sbase[NS];
    const int i = (b - 128) * 256 + tid;
    const int s = sidx[i];
    const int lane = tid & 63, w = tid >> 6;
    int myrank = 0;
#pragma unroll 1
    for (int ss = 0; ss < NS; ss++) {
      unsigned long long m = __ballot(s == ss);
      if (s == ss) myrank = (int)__popcll(m & ((1ull << lane) - 1ull));
      if (lane == 0) wcnt[w][ss] = (int)__popcll(m);
    }
    __syncthreads();
    if (tid < NS) {
      const int c0 = wcnt[0][tid], c1 = wcnt[1][tid];
      const int c2 = wcnt[2][tid], c3 = wcnt[3][tid];
      sbase[tid] = atomicAdd(&counts[tid * CPAD], c0 + c1 + c2 + c3);
      woff[0][tid] = 0;
      woff[1][tid] = c0;
      woff[2][tid] = c0 + c1;
      woff[3][tid] = c0 + c1 + c2;
    }
    __syncthreads();
    lists[(size_t)s * BATCH + sbase[s] + woff[w][s] + myrank] = (unsigned short)i;
  }
}

// ---------------------------------------------------------------------------
// main: one block = 64 rows of one state. out = relu(X@A)@C via bf16 MFMA.
//  Xs stride 136 (pad +8) -> 2-way LDS aliasing only (free).
//  B-operand fragments: Ws[n][k], lane reads 8 contiguous k -> ds_read_b128.
//  MFMA 16x16x32 bf16 layouts (HW-verified):
//    A: A[m=lane&15][k=(lane>>4)*8+j]   B: B[k=(lane>>4)*8+j][n=lane&15]
//    C/D: col=lane&15, row=(lane>>4)*4+reg
// ---------------------------------------------------------------------------
__global__ __launch_bounds__(256, 3) void ssm_kernel(
    const float* __restrict__ x,
    const int* __restrict__ counts,
    const unsigned short* __restrict__ lists,
    const unsigned short* __restrict__ At,
    const unsigned short* __restrict__ Ct,
    float* __restrict__ out) {
  __shared__ unsigned short Xs[TILE][136];  // X tile, then relu(X@A) tile
  __shared__ unsigned short Ws[D][136];     // At, then Ct
  __shared__ int rows[TILE];

  const int s = blockIdx.y;
  const int n = counts[s * CPAD];
  const int row0 = blockIdx.x * TILE;
  if (row0 >= n) return;
  const int nr = min(TILE, n - row0);
  const int tid = threadIdx.x;

  const size_t lb = (size_t)s * BATCH + row0;
  if (tid < TILE) rows[tid] = (tid < nr) ? (int)lists[lb + tid] : -1;

  // ---- stage X (gathered rows, fp32 -> bf16), 4 threads/row ----
  {
    const int r = tid >> 2, q = tid & 3;
    const int rowid = (r < nr) ? (int)lists[lb + r] : -1;
    unsigned short* xr = &Xs[r][q * 32];
    if (rowid >= 0) {
      const float4* src = (const float4*)(x + (size_t)rowid * D + q * 32);
#pragma unroll
      for (int i = 0; i < 8; i++) {
        float4 v = src[i];
        ushort4 p;
        p.x = f2bf(v.x); p.y = f2bf(v.y); p.z = f2bf(v.z); p.w = f2bf(v.w);
        *(ushort4*)(xr + i * 4) = p;
      }
    } else {
      ushort4 z; z.x = z.y = z.z = z.w = 0;
#pragma unroll
      for (int i = 0; i < 8; i++) *(ushort4*)(xr + i * 4) = z;
    }
  }
  // ---- stage At[s] -> Ws ----
  {
    const uint4* g = (const uint4*)(At + (size_t)s * D * D);
#pragma unroll
    for (int c = tid; c < 2048; c += 256)
      *(uint4*)&Ws[c >> 4][(c & 15) * 8] = g[c];
  }
  __syncthreads();

  const int lane = tid & 63, w = tid >> 6;
  const int l15 = lane & 15, quad = lane >> 4;

  f32x4 acc[8];
#pragma unroll
  for (int nb = 0; nb < 8; nb++) acc[nb] = (f32x4){0.f, 0.f, 0.f, 0.f};

  // ---- phase 1: out1 = X @ A  (wave w owns rows 16w..16w+15, all 128 cols)
#pragma unroll
  for (int kb = 0; kb < 4; kb++) {
    short8 aF = *(const short8*)&Xs[w * 16 + l15][kb * 32 + quad * 8];
#pragma unroll
    for (int nb = 0; nb < 8; nb++) {
      short8 bF = *(const short8*)&Ws[nb * 16 + l15][kb * 32 + quad * 8];
      acc[nb] = __builtin_amdgcn_mfma_f32_16x16x32_bf16(aF, bF, acc[nb], 0, 0, 0);
    }
  }
  __syncthreads();  // everyone done reading Xs and Ws

  // ---- relu + C/D-layout -> A-operand relayout through LDS ----
#pragma unroll
  for (int nb = 0; nb < 8; nb++)
#pragma unroll
    for (int r = 0; r < 4; r++) {
      float v = acc[nb][r];
      Xs[w * 16 + quad * 4 + r][nb * 16 + l15] = f2bf(v > 0.f ? v : 0.f);
    }
  // ---- stage Ct[s] -> Ws ----
  {
    const uint4* g = (const uint4*)(Ct + (size_t)s * D * D);
#pragma unroll
    for (int c = tid; c < 2048; c += 256)
      *(uint4*)&Ws[c >> 4][(c & 15) * 8] = g[c];
  }
  __syncthreads();

  // ---- phase 2: out = out1 @ C ----
#pragma unroll
  for (int nb = 0; nb < 8; nb++) acc[nb] = (f32x4){0.f, 0.f, 0.f, 0.f};
#pragma unroll
  for (int kb = 0; kb < 4; kb++) {
    short8 aF = *(const short8*)&Xs[w * 16 + l15][kb * 32 + quad * 8];
#pragma unroll
    for (int nb = 0; nb < 8; nb++) {
      short8 bF = *(const short8*)&Ws[nb * 16 + l15][kb * 32 + quad * 8];
      acc[nb] = __builtin_amdgcn_mfma_f32_16x16x32_bf16(aF, bF, acc[nb], 0, 0, 0);
    }
  }

  // ---- scatter rows back to global (fp32) ----
#pragma unroll
  for (int r = 0; r < 4; r++) {
    const int rl = w * 16 + quad * 4 + r;
    if (rl < nr) {
      float* orow = out + (size_t)rows[rl] * D + l15;
#pragma unroll
      for (int nb = 0; nb < 8; nb++) orow[nb * 16] = acc[nb][r];
    }
  }
}

extern "C" void kernel_launch(void* const* d_in, const int* in_sizes, int n_in,
                              void* d_out, int out_size, void* d_ws, size_t ws_size,
                              hipStream_t stream) {
  const float* x = (const float*)d_in[0];
  const int* sidx = (const int*)d_in[1];
  const float* A_all = (const float*)d_in[2];
  const float* C_all = (const float*)d_in[3];
  float* out = (float*)d_out;

  // ws layout: counts(16*128B=2KB) | lists(512KB u16) | At(512KB bf16) | Ct(512KB)
  int* counts = (int*)d_ws;
  unsigned short* lists = (unsigned short*)((char*)d_ws + 2048);
  unsigned short* At = (unsigned short*)((char*)d_ws + 2048 + 512 * 1024);
  unsigned short* Ct = At + NS * D * D;

  hipMemsetAsync(counts, 0, 2048, stream);
  prep_kernel<<<192, 256, 0, stream>>>(A_all, C_all, sidx, counts, lists, At, Ct);
  ssm_kernel<<<dim3(BATCH / TILE, NS), 256, 0, stream>>>(x, counts, lists, At, Ct, out);
}